// Round 3
// baseline (585.289 us; speedup 1.0000x reference)
//
#include <hip/hip_runtime.h>
#include <math.h>

#define B_ 16
#define N_ 16384
#define C_ 256
#define H_ 128
#define K_ 11468   // int(16384 * 0.7)

typedef __attribute__((ext_vector_type(8))) short s16x8;
typedef __attribute__((ext_vector_type(4))) float f32x4;

__device__ __forceinline__ unsigned short f2bf(float f) {
  unsigned u = __builtin_bit_cast(unsigned, f);
  return (unsigned short)((u + 0x7FFFu + ((u >> 16) & 1u)) >> 16);  // RNE
}
__device__ __forceinline__ float bf2f(unsigned short h) {
  unsigned u = ((unsigned)h) << 16;
  return __builtin_bit_cast(float, u);
}
// order-preserving map fp32 -> uint32 (no NaNs expected)
__device__ __forceinline__ unsigned fkey(float f) {
  unsigned u = __builtin_bit_cast(unsigned, f);
  return (u & 0x80000000u) ? ~u : (u | 0x80000000u);
}

// ---------------- w1 fp32 [C][H] -> bf16 hi/lo transposed [H][C] ----------------
__global__ void k_prep(const float* __restrict__ w1,
                       unsigned short* __restrict__ w1t_hi,
                       unsigned short* __restrict__ w1t_lo) {
  int i = blockIdx.x * blockDim.x + threadIdx.x;
  if (i < C_ * H_) {
    int c = i / H_, h = i % H_;
    float v = w1[i];
    unsigned short hi = f2bf(v);
    float lo = v - bf2f(hi);
    w1t_hi[h * C_ + c] = hi;
    w1t_lo[h * C_ + c] = f2bf(lo);
  }
}

// ---------------- fused scorer: scores = fc2(gelu(fc1(tokens))) ----------------
__global__ __launch_bounds__(256) void k_score(
    const float* __restrict__ tokens, const unsigned short* __restrict__ w1t_hi,
    const unsigned short* __restrict__ w1t_lo,
    const float* __restrict__ b1, const float* __restrict__ w2,
    const float* __restrict__ b2, float* __restrict__ scores_out) {
  const int lane = threadIdx.x & 63;
  const int l15 = lane & 15;
  const int l4 = lane >> 4;
  const int wid = (blockIdx.x * blockDim.x + threadIdx.x) >> 6;
  const int nw = (gridDim.x * blockDim.x) >> 6;

  float b1v[8], w2v[8];
#pragma unroll
  for (int nb = 0; nb < 8; ++nb) {
    b1v[nb] = b1[nb * 16 + l15];
    w2v[nb] = w2[nb * 16 + l15];
  }
  const float b2v = b2[0];

  const int G = (B_ * N_) / 16;  // 16-token groups
  for (int g = wid; g < G; g += nw) {
    const int row = g * 16 + l15;  // flat token row (b*N+n)
    const float* tp = tokens + (size_t)row * C_ + l4 * 8;
    // load 8x8 fp32 token elements, split into bf16 hi/lo fragments
    s16x8 ahi[8], alo[8];
#pragma unroll
    for (int kk = 0; kk < 8; ++kk) {
      f32x4 v0 = *reinterpret_cast<const f32x4*>(tp + kk * 32);
      f32x4 v1 = *reinterpret_cast<const f32x4*>(tp + kk * 32 + 4);
      float f[8] = {v0[0], v0[1], v0[2], v0[3], v1[0], v1[1], v1[2], v1[3]};
#pragma unroll
      for (int j = 0; j < 8; ++j) {
        unsigned short hb = f2bf(f[j]);
        ahi[kk][j] = (short)hb;
        alo[kk][j] = (short)f2bf(f[j] - bf2f(hb));
      }
    }

    f32x4 acc[8];
#pragma unroll
    for (int nb = 0; nb < 8; ++nb) acc[nb] = (f32x4){0.f, 0.f, 0.f, 0.f};

#pragma unroll
    for (int nb = 0; nb < 8; ++nb) {
      const size_t boff = (size_t)(nb * 16 + l15) * C_ + l4 * 8;
#pragma unroll
      for (int kk = 0; kk < 8; ++kk) {
        s16x8 bhi = *reinterpret_cast<const s16x8*>(w1t_hi + boff + kk * 32);
        s16x8 blo = *reinterpret_cast<const s16x8*>(w1t_lo + boff + kk * 32);
        acc[nb] = __builtin_amdgcn_mfma_f32_16x16x32_bf16(ahi[kk], bhi, acc[nb], 0, 0, 0);
        acc[nb] = __builtin_amdgcn_mfma_f32_16x16x32_bf16(ahi[kk], blo, acc[nb], 0, 0, 0);
        acc[nb] = __builtin_amdgcn_mfma_f32_16x16x32_bf16(alo[kk], bhi, acc[nb], 0, 0, 0);
      }
    }

    // epilogue: + b1, exact GELU, dot w2; D layout: col=lane&15, row=(lane>>4)*4+r
    float p[4] = {0.f, 0.f, 0.f, 0.f};
#pragma unroll
    for (int nb = 0; nb < 8; ++nb) {
#pragma unroll
      for (int r = 0; r < 4; ++r) {
        float h = acc[nb][r] + b1v[nb];
        float ge = 0.5f * h * (1.0f + erff(h * 0.70710678118654752f));
        p[r] += ge * w2v[nb];
      }
    }
#pragma unroll
    for (int r = 0; r < 4; ++r) {
      float v = p[r];
      v += __shfl_xor(v, 1);
      v += __shfl_xor(v, 2);
      v += __shfl_xor(v, 4);
      v += __shfl_xor(v, 8);
      p[r] = v + b2v;
    }
    if (l15 == 0) {
      const int rb = g * 16 + l4 * 4;
#pragma unroll
      for (int r = 0; r < 4; ++r) scores_out[rb + r] = p[r];
    }
  }
}

// ---------------- block-wide exclusive scan over 1024 threads ----------------
__device__ unsigned block_exscan_1024(unsigned v, volatile unsigned* wsum) {
  const int lane = threadIdx.x & 63;
  const int w = threadIdx.x >> 6;  // 0..15
  unsigned x = v;
#pragma unroll
  for (int d = 1; d < 64; d <<= 1) {
    unsigned t = __shfl_up(x, d);
    if (lane >= d) x += t;
  }
  if (lane == 63) wsum[w] = x;
  __syncthreads();
  if (threadIdx.x == 0) {
    unsigned s = 0;
    for (int i = 0; i < 16; ++i) {
      unsigned t = wsum[i];
      wsum[i] = s;
      s += t;
    }
  }
  __syncthreads();
  unsigned r = wsum[w] + x - v;  // exclusive
  __syncthreads();               // protect wsum for a subsequent call
  return r;
}

// ---------------- per-row top-K via radix select + stable compaction ----------------
__global__ __launch_bounds__(1024) void k_select(const float* __restrict__ scores_f,
                                                 int* __restrict__ kept,
                                                 float* __restrict__ out_idx) {
  __shared__ unsigned hist[256];
  __shared__ unsigned wsum[16];
  __shared__ unsigned sh_prefix, sh_rk;
  const int b = blockIdx.x;
  const int tid = threadIdx.x;
  const float* sp = scores_f + (size_t)b * N_;

  unsigned prefix = 0;
  unsigned rk = K_;  // elements still needed
  for (int pass = 0; pass < 4; ++pass) {
    const int shift = 24 - pass * 8;
    if (tid < 256) hist[tid] = 0;
    __syncthreads();
    const unsigned pmask = pass ? (0xFFFFFFFFu << (shift + 8)) : 0u;
    for (int i = tid; i < N_; i += 1024) {
      unsigned k = fkey(sp[i]);
      if ((k & pmask) == prefix) atomicAdd(&hist[(k >> shift) & 255u], 1u);
    }
    __syncthreads();
    if (tid == 0) {
      unsigned cum = 0;
      for (int bin = 255; bin >= 0; --bin) {
        unsigned c = hist[bin];
        if (cum + c >= rk) {
          sh_prefix = prefix | ((unsigned)bin << shift);
          sh_rk = rk - cum;
          break;
        }
        cum += c;
      }
    }
    __syncthreads();
    prefix = sh_prefix;
    rk = sh_rk;
    __syncthreads();
  }
  const unsigned Tkey = prefix;   // K-th largest key
  const unsigned need = rk;       // how many ==Tkey to keep (lowest indices first)

  // stable compaction in index order; thread owns 16 consecutive indices
  const int i0 = tid * 16;
  unsigned neq = 0;
  for (int j = 0; j < 16; ++j) {
    unsigned k = fkey(sp[i0 + j]);
    neq += (k == Tkey);
  }
  unsigned eq_base = block_exscan_1024(neq, wsum);

  unsigned kcnt = 0;
  {
    unsigned eqr = eq_base;
    for (int j = 0; j < 16; ++j) {
      unsigned k = fkey(sp[i0 + j]);
      bool kp = (k > Tkey) || ((k == Tkey) && (eqr < need));
      eqr += (k == Tkey);
      kcnt += kp;
    }
  }
  unsigned pos = block_exscan_1024(kcnt, wsum);
  {
    unsigned eqr = eq_base;
    for (int j = 0; j < 16; ++j) {
      unsigned k = fkey(sp[i0 + j]);
      bool kp = (k > Tkey) || ((k == Tkey) && (eqr < need));
      eqr += (k == Tkey);
      if (kp) {
        kept[(size_t)b * K_ + pos] = i0 + j;
        out_idx[(size_t)b * K_ + pos] = (float)(i0 + j);
        ++pos;
      }
    }
  }
}

// ---------------- gather kept token rows (fp32 -> fp32) ----------------
__global__ __launch_bounds__(256) void k_gather(const float* __restrict__ tokens,
                                                const int* __restrict__ kept,
                                                float* __restrict__ outp) {
  const int wid = (blockIdx.x * blockDim.x + threadIdx.x) >> 6;  // one wave per row
  const int lane = threadIdx.x & 63;
  if (wid >= B_ * K_) return;
  const int b = wid / K_;
  const int idx = kept[wid];
  const f32x4 v = *reinterpret_cast<const f32x4*>(tokens + ((size_t)b * N_ + idx) * C_ + lane * 4);
  *reinterpret_cast<f32x4*>(outp + (size_t)wid * C_ + lane * 4) = v;
}

extern "C" void kernel_launch(void* const* d_in, const int* in_sizes, int n_in,
                              void* d_out, int out_size, void* d_ws, size_t ws_size,
                              hipStream_t stream) {
  const float* tokens = (const float*)d_in[0];
  const float* w1 = (const float*)d_in[1];
  const float* b1 = (const float*)d_in[2];
  const float* w2 = (const float*)d_in[3];
  const float* b2 = (const float*)d_in[4];

  float* out = (float*)d_out;
  float* out_pruned = out;                                  // B*K*C fp32
  float* out_idx = out + (size_t)B_ * K_ * C_;              // B*K fp32
  float* out_scores = out_idx + (size_t)B_ * K_;            // B*N fp32

  char* ws = (char*)d_ws;
  unsigned short* w1t_hi = (unsigned short*)ws;             // 64 KB
  unsigned short* w1t_lo = (unsigned short*)(ws + 0x10000); // 64 KB
  int* kept = (int*)(ws + 0x20000);                         // B*K int32

  k_prep<<<dim3((C_ * H_ + 255) / 256), dim3(256), 0, stream>>>(w1, w1t_hi, w1t_lo);
  k_score<<<dim3(2048), dim3(256), 0, stream>>>(tokens, w1t_hi, w1t_lo, b1, w2, b2, out_scores);
  k_select<<<dim3(B_), dim3(1024), 0, stream>>>(out_scores, kept, out_idx);
  k_gather<<<dim3((B_ * K_ + 3) / 4), dim3(256), 0, stream>>>(tokens, kept, out_pruned);
}

// Round 4
// 447.165 us; speedup vs baseline: 1.3089x; 1.3089x over previous
//
#include <hip/hip_runtime.h>
#include <math.h>

#define B_ 16
#define N_ 16384
#define C_ 256
#define H_ 128
#define K_ 11468   // int(16384 * 0.7)
#define G_ ((B_ * N_) / 16)

typedef __attribute__((ext_vector_type(8))) short s16x8;
typedef __attribute__((ext_vector_type(4))) float f32x4;
typedef __attribute__((ext_vector_type(4))) unsigned int u32x4;

__device__ __forceinline__ unsigned short f2bf(float f) {
  unsigned u = __builtin_bit_cast(unsigned, f);
  return (unsigned short)((u + 0x7FFFu + ((u >> 16) & 1u)) >> 16);  // RNE
}
// order-preserving map fp32 -> uint32 (no NaNs expected)
__device__ __forceinline__ unsigned fkey(float f) {
  unsigned u = __builtin_bit_cast(unsigned, f);
  return (u & 0x80000000u) ? ~u : (u | 0x80000000u);
}

// ---- w1 fp32 [C][H] -> bf16 [H][C] with XOR-swizzled 16B chunks (LDS-ready) ----
// chunk (r, c16) stored at chunk position (c16 ^ (r & 31)) within row r.
__global__ void k_prep(const float* __restrict__ w1, unsigned short* __restrict__ w1sw) {
  int i = blockIdx.x * blockDim.x + threadIdx.x;  // i = c*H + r over w1
  if (i < C_ * H_) {
    int c = i / H_, r = i % H_;
    int c16 = c >> 3, j = c & 7;
    w1sw[r * 256 + ((c16 ^ (r & 31)) << 3) + j] = f2bf(w1[i]);
  }
}

// ---------------- fused scorer: scores = fc2(gelu(fc1(tokens))) ----------------
__global__ __launch_bounds__(512, 4) void k_score(
    const float* __restrict__ tokens, const unsigned short* __restrict__ w1sw,
    const float* __restrict__ b1, const float* __restrict__ w2,
    const float* __restrict__ b2, float* __restrict__ scores_out) {
  __shared__ unsigned short lds[H_ * C_];  // 64 KB, swizzled bf16 W1^T

  // stage ws -> LDS (linear copy; swizzle already baked into ws contents)
  {
    const f32x4* src = reinterpret_cast<const f32x4*>(w1sw);
    f32x4* dst = reinterpret_cast<f32x4*>(lds);
    const int t = threadIdx.x;
#pragma unroll
    for (int i = 0; i < 8; ++i) dst[t + i * 512] = src[t + i * 512];
  }
  __syncthreads();

  const int lane = threadIdx.x & 63;
  const int l15 = lane & 15;
  const int l4 = lane >> 4;
  const int wid = (blockIdx.x * blockDim.x + threadIdx.x) >> 6;
  const int nw = (gridDim.x * blockDim.x) >> 6;

  float b1v[8], w2v[8];
#pragma unroll
  for (int nb = 0; nb < 8; ++nb) {
    b1v[nb] = b1[nb * 16 + l15];
    w2v[nb] = w2[nb * 16 + l15];
  }
  const float b2v = b2[0];

  for (int g = wid; g < G_; g += nw) {
    const float* tp = tokens + (size_t)(g * 16 + l15) * C_ + l4 * 8;
    // load 64 fp32/lane, pack to bf16 (truncation) via v_perm: 1 op per 2 elems
    u32x4 a[8];
#pragma unroll
    for (int kk = 0; kk < 8; ++kk) {
      f32x4 v0 = *reinterpret_cast<const f32x4*>(tp + kk * 32);
      f32x4 v1 = *reinterpret_cast<const f32x4*>(tp + kk * 32 + 4);
      a[kk][0] = __builtin_amdgcn_perm(__builtin_bit_cast(unsigned, v0[1]),
                                       __builtin_bit_cast(unsigned, v0[0]), 0x07060302u);
      a[kk][1] = __builtin_amdgcn_perm(__builtin_bit_cast(unsigned, v0[3]),
                                       __builtin_bit_cast(unsigned, v0[2]), 0x07060302u);
      a[kk][2] = __builtin_amdgcn_perm(__builtin_bit_cast(unsigned, v1[1]),
                                       __builtin_bit_cast(unsigned, v1[0]), 0x07060302u);
      a[kk][3] = __builtin_amdgcn_perm(__builtin_bit_cast(unsigned, v1[3]),
                                       __builtin_bit_cast(unsigned, v1[2]), 0x07060302u);
    }

    f32x4 acc[8];
#pragma unroll
    for (int nb = 0; nb < 8; ++nb) acc[nb] = (f32x4){0.f, 0.f, 0.f, 0.f};

#pragma unroll
    for (int nb = 0; nb < 8; ++nb) {
      const int rbase = nb * 16 + l15;  // hidden row in [0,128)
      const int rlo = rbase & 31;
#pragma unroll
      for (int kk = 0; kk < 8; ++kk) {
        const int cpos = (l4 + kk * 4) ^ rlo;  // swizzled 16B-chunk position
        s16x8 bf = *reinterpret_cast<const s16x8*>(lds + rbase * 256 + (cpos << 3));
        acc[nb] = __builtin_amdgcn_mfma_f32_16x16x32_bf16(
            __builtin_bit_cast(s16x8, a[kk]), bf, acc[nb], 0, 0, 0);
      }
    }

    // epilogue: + b1, exact GELU, dot w2; D layout: col=lane&15, row=(lane>>4)*4+r
    float p[4] = {0.f, 0.f, 0.f, 0.f};
#pragma unroll
    for (int nb = 0; nb < 8; ++nb) {
#pragma unroll
      for (int r = 0; r < 4; ++r) {
        float h = acc[nb][r] + b1v[nb];
        float ge = 0.5f * h * (1.0f + erff(h * 0.70710678118654752f));
        p[r] += ge * w2v[nb];
      }
    }
#pragma unroll
    for (int r = 0; r < 4; ++r) {
      float v = p[r];
      v += __shfl_xor(v, 1);
      v += __shfl_xor(v, 2);
      v += __shfl_xor(v, 4);
      v += __shfl_xor(v, 8);
      p[r] = v + b2v;
    }
    if (l15 == 0) {
      const int rb = g * 16 + l4 * 4;
#pragma unroll
      for (int r = 0; r < 4; ++r) scores_out[rb + r] = p[r];
    }
  }
}

// ---------------- block-wide exclusive scan over 1024 threads ----------------
__device__ unsigned block_exscan_1024(unsigned v, volatile unsigned* wsum) {
  const int lane = threadIdx.x & 63;
  const int w = threadIdx.x >> 6;  // 0..15
  unsigned x = v;
#pragma unroll
  for (int d = 1; d < 64; d <<= 1) {
    unsigned t = __shfl_up(x, d);
    if (lane >= d) x += t;
  }
  if (lane == 63) wsum[w] = x;
  __syncthreads();
  if (threadIdx.x == 0) {
    unsigned s = 0;
    for (int i = 0; i < 16; ++i) {
      unsigned t = wsum[i];
      wsum[i] = s;
      s += t;
    }
  }
  __syncthreads();
  unsigned r = wsum[w] + x - v;  // exclusive
  __syncthreads();               // protect wsum for a subsequent call
  return r;
}

// ---------------- per-row top-K via radix select + stable compaction ----------------
__global__ __launch_bounds__(1024) void k_select(const float* __restrict__ scores_f,
                                                 int* __restrict__ kept,
                                                 float* __restrict__ out_idx) {
  __shared__ unsigned hist[256];
  __shared__ unsigned wsum[16];
  __shared__ unsigned sh_prefix, sh_rk;
  const int b = blockIdx.x;
  const int tid = threadIdx.x;
  const float* sp = scores_f + (size_t)b * N_;

  unsigned prefix = 0;
  unsigned rk = K_;  // elements still needed
  for (int pass = 0; pass < 4; ++pass) {
    const int shift = 24 - pass * 8;
    if (tid < 256) hist[tid] = 0;
    __syncthreads();
    const unsigned pmask = pass ? (0xFFFFFFFFu << (shift + 8)) : 0u;
    for (int i = tid; i < N_; i += 1024) {
      unsigned k = fkey(sp[i]);
      if ((k & pmask) == prefix) atomicAdd(&hist[(k >> shift) & 255u], 1u);
    }
    __syncthreads();
    // parallel bin search: suffix-sum via reversed block scan
    unsigned h = (tid < 256) ? hist[255 - tid] : 0u;
    unsigned s = block_exscan_1024(h, wsum);  // s = count of keys in bins > (255-tid)
    if (tid < 256 && s < rk && s + h >= rk) {
      sh_prefix = prefix | ((unsigned)(255 - tid) << shift);
      sh_rk = rk - s;
    }
    __syncthreads();
    prefix = sh_prefix;
    rk = sh_rk;
    __syncthreads();
  }
  const unsigned Tkey = prefix;   // K-th largest key
  const unsigned need = rk;       // how many ==Tkey to keep (lowest indices first)

  // stable compaction in index order; thread owns 16 consecutive indices
  const int i0 = tid * 16;
  unsigned neq = 0;
  for (int j = 0; j < 16; ++j) {
    unsigned k = fkey(sp[i0 + j]);
    neq += (k == Tkey);
  }
  unsigned eq_base = block_exscan_1024(neq, wsum);

  unsigned kcnt = 0;
  {
    unsigned eqr = eq_base;
    for (int j = 0; j < 16; ++j) {
      unsigned k = fkey(sp[i0 + j]);
      bool kp = (k > Tkey) || ((k == Tkey) && (eqr < need));
      eqr += (k == Tkey);
      kcnt += kp;
    }
  }
  unsigned pos = block_exscan_1024(kcnt, wsum);
  {
    unsigned eqr = eq_base;
    for (int j = 0; j < 16; ++j) {
      unsigned k = fkey(sp[i0 + j]);
      bool kp = (k > Tkey) || ((k == Tkey) && (eqr < need));
      eqr += (k == Tkey);
      if (kp) {
        kept[(size_t)b * K_ + pos] = i0 + j;
        out_idx[(size_t)b * K_ + pos] = (float)(i0 + j);
        ++pos;
      }
    }
  }
}

// ---------------- gather kept token rows (fp32 -> fp32) ----------------
__global__ __launch_bounds__(256) void k_gather(const float* __restrict__ tokens,
                                                const int* __restrict__ kept,
                                                float* __restrict__ outp) {
  const int wid = (blockIdx.x * blockDim.x + threadIdx.x) >> 6;  // one wave per row
  const int lane = threadIdx.x & 63;
  if (wid >= B_ * K_) return;
  const int b = wid / K_;
  const int idx = kept[wid];
  const f32x4 v = *reinterpret_cast<const f32x4*>(tokens + ((size_t)b * N_ + idx) * C_ + lane * 4);
  *reinterpret_cast<f32x4*>(outp + (size_t)wid * C_ + lane * 4) = v;
}

extern "C" void kernel_launch(void* const* d_in, const int* in_sizes, int n_in,
                              void* d_out, int out_size, void* d_ws, size_t ws_size,
                              hipStream_t stream) {
  const float* tokens = (const float*)d_in[0];
  const float* w1 = (const float*)d_in[1];
  const float* b1 = (const float*)d_in[2];
  const float* w2 = (const float*)d_in[3];
  const float* b2 = (const float*)d_in[4];

  float* out = (float*)d_out;
  float* out_pruned = out;                                  // B*K*C fp32
  float* out_idx = out + (size_t)B_ * K_ * C_;              // B*K fp32
  float* out_scores = out_idx + (size_t)B_ * K_;            // B*N fp32

  char* ws = (char*)d_ws;
  unsigned short* w1sw = (unsigned short*)ws;               // 64 KB swizzled bf16
  int* kept = (int*)(ws + 0x10000);                         // B*K int32

  k_prep<<<dim3((C_ * H_ + 255) / 256), dim3(256), 0, stream>>>(w1, w1sw);
  k_score<<<dim3(512), dim3(512), 0, stream>>>(tokens, w1sw, b1, w2, b2, out_scores);
  k_select<<<dim3(B_), dim3(1024), 0, stream>>>(out_scores, kept, out_idx);
  k_gather<<<dim3((B_ * K_ + 3) / 4), dim3(256), 0, stream>>>(tokens, kept, out_pruned);
}

// Round 5
// 439.549 us; speedup vs baseline: 1.3316x; 1.0173x over previous
//
#include <hip/hip_runtime.h>
#include <math.h>

#define B_ 16
#define N_ 16384
#define C_ 256
#define H_ 128
#define K_ 11468   // int(16384 * 0.7)
#define G_ ((B_ * N_) / 16)

typedef __attribute__((ext_vector_type(8))) short s16x8;
typedef __attribute__((ext_vector_type(4))) float f32x4;
typedef __attribute__((ext_vector_type(4))) unsigned int u32x4;

__device__ __forceinline__ unsigned short f2bf(float f) {
  unsigned u = __builtin_bit_cast(unsigned, f);
  return (unsigned short)((u + 0x7FFFu + ((u >> 16) & 1u)) >> 16);  // RNE
}
// order-preserving map fp32 -> uint32 (no NaNs expected)
__device__ __forceinline__ unsigned fkey(float f) {
  unsigned u = __builtin_bit_cast(unsigned, f);
  return (u & 0x80000000u) ? ~u : (u | 0x80000000u);
}

// ---- w1 fp32 [C][H] -> bf16 [H][C] with XOR-swizzled 16B chunks (LDS-ready) ----
// chunk (r, c16) stored at chunk position (c16 ^ (r & 31)) within row r.
__global__ void k_prep(const float* __restrict__ w1, unsigned short* __restrict__ w1sw) {
  int i = blockIdx.x * blockDim.x + threadIdx.x;  // i = c*H + r over w1
  if (i < C_ * H_) {
    int c = i / H_, r = i % H_;
    int c16 = c >> 3, j = c & 7;
    w1sw[r * 256 + ((c16 ^ (r & 31)) << 3) + j] = f2bf(w1[i]);
  }
}

// ---------------- fused scorer: scores = fc2(gelu(fc1(tokens))) ----------------
__global__ void __launch_bounds__(512)
    __attribute__((amdgpu_waves_per_eu(4, 4))) k_score(
    const float* __restrict__ tokens, const unsigned short* __restrict__ w1sw,
    const float* __restrict__ b1, const float* __restrict__ w2,
    const float* __restrict__ b2, float* __restrict__ scores_out) {
  __shared__ unsigned short lds[H_ * C_];  // 64 KB, swizzled bf16 W1^T

  // stage ws -> LDS (linear copy; swizzle already baked into ws contents)
  {
    const f32x4* src = reinterpret_cast<const f32x4*>(w1sw);
    f32x4* dst = reinterpret_cast<f32x4*>(lds);
    const int t = threadIdx.x;
#pragma unroll
    for (int i = 0; i < 8; ++i) dst[t + i * 512] = src[t + i * 512];
  }
  __syncthreads();

  const int lane = threadIdx.x & 63;
  const int l15 = lane & 15;
  const int l4 = lane >> 4;
  const int wid = (blockIdx.x * blockDim.x + threadIdx.x) >> 6;
  const int nw = (gridDim.x * blockDim.x) >> 6;

  for (int g = wid; g < G_; g += nw) {
    const float* tp = tokens + (size_t)(g * 16 + l15) * C_ + l4 * 8;
    // issue all 16 16B loads upfront (deep in-flight queue for HBM BW)
    f32x4 v[16];
#pragma unroll
    for (int kk = 0; kk < 8; ++kk) {
      v[2 * kk] = *reinterpret_cast<const f32x4*>(tp + kk * 32);
      v[2 * kk + 1] = *reinterpret_cast<const f32x4*>(tp + kk * 32 + 4);
    }

    f32x4 acc[8];
#pragma unroll
    for (int nb = 0; nb < 8; ++nb) acc[nb] = (f32x4){0.f, 0.f, 0.f, 0.f};

#pragma unroll
    for (int kk = 0; kk < 8; ++kk) {
      // pack 8 fp32 -> 8 bf16 (truncation) via v_perm, consuming v[2kk],v[2kk+1]
      u32x4 a;
      a[0] = __builtin_amdgcn_perm(__builtin_bit_cast(unsigned, v[2 * kk][1]),
                                   __builtin_bit_cast(unsigned, v[2 * kk][0]), 0x07060302u);
      a[1] = __builtin_amdgcn_perm(__builtin_bit_cast(unsigned, v[2 * kk][3]),
                                   __builtin_bit_cast(unsigned, v[2 * kk][2]), 0x07060302u);
      a[2] = __builtin_amdgcn_perm(__builtin_bit_cast(unsigned, v[2 * kk + 1][1]),
                                   __builtin_bit_cast(unsigned, v[2 * kk + 1][0]), 0x07060302u);
      a[3] = __builtin_amdgcn_perm(__builtin_bit_cast(unsigned, v[2 * kk + 1][3]),
                                   __builtin_bit_cast(unsigned, v[2 * kk + 1][2]), 0x07060302u);
      const int e0 = (((l4 + kk * 4) ^ l15) << 3);  // ushort offset of swizzled chunk (even nb)
#pragma unroll
      for (int nb = 0; nb < 8; ++nb) {
        const int off = (nb & 1) ? (e0 ^ 128) : e0;  // odd nb: row|16 -> toggle chunk bit4
        s16x8 bf = *reinterpret_cast<const s16x8*>(lds + nb * 4096 + l15 * 256 + off);
        acc[nb] = __builtin_amdgcn_mfma_f32_16x16x32_bf16(
            __builtin_bit_cast(s16x8, a), bf, acc[nb], 0, 0, 0);
      }
    }

    // epilogue: + b1, exact GELU, dot w2; D layout: col=lane&15, row=(lane>>4)*4+r
    float p[4] = {0.f, 0.f, 0.f, 0.f};
#pragma unroll
    for (int nb = 0; nb < 8; ++nb) {
      const float b1v = b1[nb * 16 + l15];
      const float w2v = w2[nb * 16 + l15];
#pragma unroll
      for (int r = 0; r < 4; ++r) {
        float h = acc[nb][r] + b1v;
        float ge = 0.5f * h * (1.0f + erff(h * 0.70710678118654752f));
        p[r] += ge * w2v;
      }
    }
    const float b2v = b2[0];
#pragma unroll
    for (int r = 0; r < 4; ++r) {
      float s = p[r];
      s += __shfl_xor(s, 1);
      s += __shfl_xor(s, 2);
      s += __shfl_xor(s, 4);
      s += __shfl_xor(s, 8);
      p[r] = s + b2v;
    }
    if (l15 == 0) {
      const int rb = g * 16 + l4 * 4;
#pragma unroll
      for (int r = 0; r < 4; ++r) scores_out[rb + r] = p[r];
    }
  }
}

// ---------------- block-wide exclusive scan over 1024 threads ----------------
__device__ unsigned block_exscan_1024(unsigned v, volatile unsigned* wsum) {
  const int lane = threadIdx.x & 63;
  const int w = threadIdx.x >> 6;  // 0..15
  unsigned x = v;
#pragma unroll
  for (int d = 1; d < 64; d <<= 1) {
    unsigned t = __shfl_up(x, d);
    if (lane >= d) x += t;
  }
  if (lane == 63) wsum[w] = x;
  __syncthreads();
  if (threadIdx.x == 0) {
    unsigned s = 0;
    for (int i = 0; i < 16; ++i) {
      unsigned t = wsum[i];
      wsum[i] = s;
      s += t;
    }
  }
  __syncthreads();
  unsigned r = wsum[w] + x - v;  // exclusive
  __syncthreads();               // protect wsum for a subsequent call
  return r;
}

// ---------------- per-row top-K via radix select + stable compaction ----------------
__global__ __launch_bounds__(1024) void k_select(const float* __restrict__ scores_f,
                                                 int* __restrict__ kept,
                                                 float* __restrict__ out_idx) {
  __shared__ unsigned hist[256];
  __shared__ unsigned wsum[16];
  __shared__ unsigned sh_prefix, sh_rk;
  const int b = blockIdx.x;
  const int tid = threadIdx.x;
  const float* sp = scores_f + (size_t)b * N_;

  unsigned prefix = 0;
  unsigned rk = K_;  // elements still needed
  for (int pass = 0; pass < 4; ++pass) {
    const int shift = 24 - pass * 8;
    if (tid < 256) hist[tid] = 0;
    __syncthreads();
    const unsigned pmask = pass ? (0xFFFFFFFFu << (shift + 8)) : 0u;
    for (int i = tid; i < N_; i += 1024) {
      unsigned k = fkey(sp[i]);
      if ((k & pmask) == prefix) atomicAdd(&hist[(k >> shift) & 255u], 1u);
    }
    __syncthreads();
    // parallel bin search: suffix-sum via reversed block scan
    unsigned h = (tid < 256) ? hist[255 - tid] : 0u;
    unsigned s = block_exscan_1024(h, wsum);  // s = count of keys in bins > (255-tid)
    if (tid < 256 && s < rk && s + h >= rk) {
      sh_prefix = prefix | ((unsigned)(255 - tid) << shift);
      sh_rk = rk - s;
    }
    __syncthreads();
    prefix = sh_prefix;
    rk = sh_rk;
    __syncthreads();
  }
  const unsigned Tkey = prefix;   // K-th largest key
  const unsigned need = rk;       // how many ==Tkey to keep (lowest indices first)

  // stable compaction in index order; thread owns 16 consecutive indices
  const int i0 = tid * 16;
  unsigned neq = 0;
  for (int j = 0; j < 16; ++j) {
    unsigned k = fkey(sp[i0 + j]);
    neq += (k == Tkey);
  }
  unsigned eq_base = block_exscan_1024(neq, wsum);

  unsigned kcnt = 0;
  {
    unsigned eqr = eq_base;
    for (int j = 0; j < 16; ++j) {
      unsigned k = fkey(sp[i0 + j]);
      bool kp = (k > Tkey) || ((k == Tkey) && (eqr < need));
      eqr += (k == Tkey);
      kcnt += kp;
    }
  }
  unsigned pos = block_exscan_1024(kcnt, wsum);
  {
    unsigned eqr = eq_base;
    for (int j = 0; j < 16; ++j) {
      unsigned k = fkey(sp[i0 + j]);
      bool kp = (k > Tkey) || ((k == Tkey) && (eqr < need));
      eqr += (k == Tkey);
      if (kp) {
        kept[(size_t)b * K_ + pos] = i0 + j;
        out_idx[(size_t)b * K_ + pos] = (float)(i0 + j);
        ++pos;
      }
    }
  }
}

// ---------------- gather kept token rows (fp32 -> fp32) ----------------
__global__ __launch_bounds__(256) void k_gather(const float* __restrict__ tokens,
                                                const int* __restrict__ kept,
                                                float* __restrict__ outp) {
  const int wid = (blockIdx.x * blockDim.x + threadIdx.x) >> 6;  // one wave per row
  const int lane = threadIdx.x & 63;
  if (wid >= B_ * K_) return;
  const int b = wid / K_;
  const int idx = kept[wid];
  const f32x4 v = *reinterpret_cast<const f32x4*>(tokens + ((size_t)b * N_ + idx) * C_ + lane * 4);
  *reinterpret_cast<f32x4*>(outp + (size_t)wid * C_ + lane * 4) = v;
}

extern "C" void kernel_launch(void* const* d_in, const int* in_sizes, int n_in,
                              void* d_out, int out_size, void* d_ws, size_t ws_size,
                              hipStream_t stream) {
  const float* tokens = (const float*)d_in[0];
  const float* w1 = (const float*)d_in[1];
  const float* b1 = (const float*)d_in[2];
  const float* w2 = (const float*)d_in[3];
  const float* b2 = (const float*)d_in[4];

  float* out = (float*)d_out;
  float* out_pruned = out;                                  // B*K*C fp32
  float* out_idx = out + (size_t)B_ * K_ * C_;              // B*K fp32
  float* out_scores = out_idx + (size_t)B_ * K_;            // B*N fp32

  char* ws = (char*)d_ws;
  unsigned short* w1sw = (unsigned short*)ws;               // 64 KB swizzled bf16
  int* kept = (int*)(ws + 0x10000);                         // B*K int32

  k_prep<<<dim3((C_ * H_ + 255) / 256), dim3(256), 0, stream>>>(w1, w1sw);
  k_score<<<dim3(512), dim3(512), 0, stream>>>(tokens, w1sw, b1, w2, b2, out_scores);
  k_select<<<dim3(B_), dim3(1024), 0, stream>>>(out_scores, kept, out_idx);
  k_gather<<<dim3((B_ * K_ + 3) / 4), dim3(256), 0, stream>>>(tokens, kept, out_pruned);
}

// Round 6
// 253.808 us; speedup vs baseline: 2.3060x; 1.7318x over previous
//
#include <hip/hip_runtime.h>
#include <math.h>

#define B_ 16
#define N_ 16384
#define C_ 256
#define H_ 128
#define K_ 11468   // int(16384 * 0.7)
#define G_ ((B_ * N_) / 16)

typedef __attribute__((ext_vector_type(8))) short s16x8;
typedef __attribute__((ext_vector_type(4))) float f32x4;
typedef __attribute__((ext_vector_type(4))) unsigned int u32x4;

__device__ __forceinline__ unsigned short f2bf(float f) {
  unsigned u = __builtin_bit_cast(unsigned, f);
  return (unsigned short)((u + 0x7FFFu + ((u >> 16) & 1u)) >> 16);  // RNE
}
// order-preserving map fp32 -> uint32 (no NaNs expected)
__device__ __forceinline__ unsigned fkey(float f) {
  unsigned u = __builtin_bit_cast(unsigned, f);
  return (u & 0x80000000u) ? ~u : (u | 0x80000000u);
}

// ---- w1 fp32 [C][H] -> bf16 [H][C] with XOR-swizzled 16B chunks (LDS-ready) ----
// chunk (r, c16) stored at chunk position (c16 ^ (r & 31)) within row r.
__global__ void k_prep(const float* __restrict__ w1, unsigned short* __restrict__ w1sw) {
  int i = blockIdx.x * blockDim.x + threadIdx.x;  // i = c*H + r over w1
  if (i < C_ * H_) {
    int c = i / H_, r = i % H_;
    int c16 = c >> 3, j = c & 7;
    w1sw[r * 256 + ((c16 ^ (r & 31)) << 3) + j] = f2bf(w1[i]);
  }
}

// ---------------- fused scorer: scores = fc2(gelu(fc1(tokens))) ----------------
// 256-thread blocks + bare launch_bounds: occupancy is LDS-capped at 2 blocks/CU
// (8 waves/CU) for any VGPR count in [129,256], so let the allocator run free —
// this is what kills the 64-VGPR/scratch-spill pathology of rounds 4/5.
__global__ __launch_bounds__(256) void k_score(
    const float* __restrict__ tokens, const unsigned short* __restrict__ w1sw,
    const float* __restrict__ b1, const float* __restrict__ w2,
    const float* __restrict__ b2, float* __restrict__ scores_out) {
  __shared__ unsigned short lds[H_ * C_];  // 64 KB, swizzled bf16 W1^T

  // stage ws -> LDS (linear copy; swizzle already baked into ws contents)
  {
    const f32x4* src = reinterpret_cast<const f32x4*>(w1sw);
    f32x4* dst = reinterpret_cast<f32x4*>(lds);
    const int t = threadIdx.x;
#pragma unroll
    for (int i = 0; i < 16; ++i) dst[t + i * 256] = src[t + i * 256];
  }
  __syncthreads();

  const int lane = threadIdx.x & 63;
  const int l15 = lane & 15;
  const int l4 = lane >> 4;
  const int wid = (blockIdx.x * blockDim.x + threadIdx.x) >> 6;
  const int nw = (gridDim.x * blockDim.x) >> 6;

  for (int g = wid; g < G_; g += nw) {
    const float* tp = tokens + (size_t)(g * 16 + l15) * C_ + l4 * 8;
    // issue all 16 16B loads upfront (deep in-flight queue for HBM BW)
    f32x4 v[16];
#pragma unroll
    for (int kk = 0; kk < 8; ++kk) {
      v[2 * kk] = *reinterpret_cast<const f32x4*>(tp + kk * 32);
      v[2 * kk + 1] = *reinterpret_cast<const f32x4*>(tp + kk * 32 + 4);
    }

    f32x4 acc[8];
#pragma unroll
    for (int nb = 0; nb < 8; ++nb) acc[nb] = (f32x4){0.f, 0.f, 0.f, 0.f};

#pragma unroll
    for (int kk = 0; kk < 8; ++kk) {
      // pack 8 fp32 -> 8 bf16 (truncation) via v_perm, consuming v[2kk],v[2kk+1]
      u32x4 a;
      a[0] = __builtin_amdgcn_perm(__builtin_bit_cast(unsigned, v[2 * kk][1]),
                                   __builtin_bit_cast(unsigned, v[2 * kk][0]), 0x07060302u);
      a[1] = __builtin_amdgcn_perm(__builtin_bit_cast(unsigned, v[2 * kk][3]),
                                   __builtin_bit_cast(unsigned, v[2 * kk][2]), 0x07060302u);
      a[2] = __builtin_amdgcn_perm(__builtin_bit_cast(unsigned, v[2 * kk + 1][1]),
                                   __builtin_bit_cast(unsigned, v[2 * kk + 1][0]), 0x07060302u);
      a[3] = __builtin_amdgcn_perm(__builtin_bit_cast(unsigned, v[2 * kk + 1][3]),
                                   __builtin_bit_cast(unsigned, v[2 * kk + 1][2]), 0x07060302u);
      const int e0 = (((l4 + kk * 4) ^ l15) << 3);  // ushort offset of swizzled chunk (even nb)
#pragma unroll
      for (int nb = 0; nb < 8; ++nb) {
        const int off = (nb & 1) ? (e0 ^ 128) : e0;  // odd nb: row|16 -> toggle chunk bit4
        s16x8 bf = *reinterpret_cast<const s16x8*>(lds + nb * 4096 + l15 * 256 + off);
        acc[nb] = __builtin_amdgcn_mfma_f32_16x16x32_bf16(
            __builtin_bit_cast(s16x8, a), bf, acc[nb], 0, 0, 0);
      }
    }

    // epilogue: + b1, exact GELU, dot w2; D layout: col=lane&15, row=(lane>>4)*4+r
    float p[4] = {0.f, 0.f, 0.f, 0.f};
#pragma unroll
    for (int nb = 0; nb < 8; ++nb) {
      const float b1v = b1[nb * 16 + l15];
      const float w2v = w2[nb * 16 + l15];
#pragma unroll
      for (int r = 0; r < 4; ++r) {
        float h = acc[nb][r] + b1v;
        float ge = 0.5f * h * (1.0f + erff(h * 0.70710678118654752f));
        p[r] += ge * w2v;
      }
    }
    const float b2v = b2[0];
#pragma unroll
    for (int r = 0; r < 4; ++r) {
      float s = p[r];
      s += __shfl_xor(s, 1);
      s += __shfl_xor(s, 2);
      s += __shfl_xor(s, 4);
      s += __shfl_xor(s, 8);
      p[r] = s + b2v;
    }
    if (l15 == 0) {
      const int rb = g * 16 + l4 * 4;
#pragma unroll
      for (int r = 0; r < 4; ++r) scores_out[rb + r] = p[r];
    }
  }
}

// ---------------- block-wide exclusive scan over 1024 threads ----------------
__device__ unsigned block_exscan_1024(unsigned v, volatile unsigned* wsum) {
  const int lane = threadIdx.x & 63;
  const int w = threadIdx.x >> 6;  // 0..15
  unsigned x = v;
#pragma unroll
  for (int d = 1; d < 64; d <<= 1) {
    unsigned t = __shfl_up(x, d);
    if (lane >= d) x += t;
  }
  if (lane == 63) wsum[w] = x;
  __syncthreads();
  if (threadIdx.x == 0) {
    unsigned s = 0;
    for (int i = 0; i < 16; ++i) {
      unsigned t = wsum[i];
      wsum[i] = s;
      s += t;
    }
  }
  __syncthreads();
  unsigned r = wsum[w] + x - v;  // exclusive
  __syncthreads();               // protect wsum for a subsequent call
  return r;
}

// ---------------- per-row top-K via radix select + stable compaction ----------------
__global__ __launch_bounds__(1024) void k_select(const float* __restrict__ scores_f,
                                                 int* __restrict__ kept,
                                                 float* __restrict__ out_idx) {
  __shared__ unsigned hist[256];
  __shared__ unsigned wsum[16];
  __shared__ unsigned sh_prefix, sh_rk;
  const int b = blockIdx.x;
  const int tid = threadIdx.x;
  const float* sp = scores_f + (size_t)b * N_;

  unsigned prefix = 0;
  unsigned rk = K_;  // elements still needed
  for (int pass = 0; pass < 4; ++pass) {
    const int shift = 24 - pass * 8;
    if (tid < 256) hist[tid] = 0;
    __syncthreads();
    const unsigned pmask = pass ? (0xFFFFFFFFu << (shift + 8)) : 0u;
    for (int i = tid; i < N_; i += 1024) {
      unsigned k = fkey(sp[i]);
      if ((k & pmask) == prefix) atomicAdd(&hist[(k >> shift) & 255u], 1u);
    }
    __syncthreads();
    // parallel bin search: suffix-sum via reversed block scan
    unsigned h = (tid < 256) ? hist[255 - tid] : 0u;
    unsigned s = block_exscan_1024(h, wsum);  // s = count of keys in bins > (255-tid)
    if (tid < 256 && s < rk && s + h >= rk) {
      sh_prefix = prefix | ((unsigned)(255 - tid) << shift);
      sh_rk = rk - s;
    }
    __syncthreads();
    prefix = sh_prefix;
    rk = sh_rk;
    __syncthreads();
  }
  const unsigned Tkey = prefix;   // K-th largest key
  const unsigned need = rk;       // how many ==Tkey to keep (lowest indices first)

  // stable compaction in index order; thread owns 16 consecutive indices
  const int i0 = tid * 16;
  unsigned neq = 0;
  for (int j = 0; j < 16; ++j) {
    unsigned k = fkey(sp[i0 + j]);
    neq += (k == Tkey);
  }
  unsigned eq_base = block_exscan_1024(neq, wsum);

  unsigned kcnt = 0;
  {
    unsigned eqr = eq_base;
    for (int j = 0; j < 16; ++j) {
      unsigned k = fkey(sp[i0 + j]);
      bool kp = (k > Tkey) || ((k == Tkey) && (eqr < need));
      eqr += (k == Tkey);
      kcnt += kp;
    }
  }
  unsigned pos = block_exscan_1024(kcnt, wsum);
  {
    unsigned eqr = eq_base;
    for (int j = 0; j < 16; ++j) {
      unsigned k = fkey(sp[i0 + j]);
      bool kp = (k > Tkey) || ((k == Tkey) && (eqr < need));
      eqr += (k == Tkey);
      if (kp) {
        kept[(size_t)b * K_ + pos] = i0 + j;
        out_idx[(size_t)b * K_ + pos] = (float)(i0 + j);
        ++pos;
      }
    }
  }
}

// ---------------- gather kept token rows (fp32 -> fp32) ----------------
__global__ __launch_bounds__(256) void k_gather(const float* __restrict__ tokens,
                                                const int* __restrict__ kept,
                                                float* __restrict__ outp) {
  const int wid = (blockIdx.x * blockDim.x + threadIdx.x) >> 6;  // one wave per row
  const int lane = threadIdx.x & 63;
  if (wid >= B_ * K_) return;
  const int b = wid / K_;
  const int idx = kept[wid];
  const f32x4 v = *reinterpret_cast<const f32x4*>(tokens + ((size_t)b * N_ + idx) * C_ + lane * 4);
  *reinterpret_cast<f32x4*>(outp + (size_t)wid * C_ + lane * 4) = v;
}

extern "C" void kernel_launch(void* const* d_in, const int* in_sizes, int n_in,
                              void* d_out, int out_size, void* d_ws, size_t ws_size,
                              hipStream_t stream) {
  const float* tokens = (const float*)d_in[0];
  const float* w1 = (const float*)d_in[1];
  const float* b1 = (const float*)d_in[2];
  const float* w2 = (const float*)d_in[3];
  const float* b2 = (const float*)d_in[4];

  float* out = (float*)d_out;
  float* out_pruned = out;                                  // B*K*C fp32
  float* out_idx = out + (size_t)B_ * K_ * C_;              // B*K fp32
  float* out_scores = out_idx + (size_t)B_ * K_;            // B*N fp32

  char* ws = (char*)d_ws;
  unsigned short* w1sw = (unsigned short*)ws;               // 64 KB swizzled bf16
  int* kept = (int*)(ws + 0x10000);                         // B*K int32

  k_prep<<<dim3((C_ * H_ + 255) / 256), dim3(256), 0, stream>>>(w1, w1sw);
  k_score<<<dim3(1024), dim3(256), 0, stream>>>(tokens, w1sw, b1, w2, b2, out_scores);
  k_select<<<dim3(B_), dim3(1024), 0, stream>>>(out_scores, kept, out_idx);
  k_gather<<<dim3((B_ * K_ + 3) / 4), dim3(256), 0, stream>>>(tokens, kept, out_pruned);
}